// Round 20
// baseline (44.976 us; speedup 1.0000x reference)
//
#include <hip/hip_runtime.h>
#include <hip/hip_bf16.h>

#define NN 512
#define FIN 128
#define HH 4
#define DD 64
#define SW 68   // permuted/padded e-width: 17 groups x 4
// lrelu(z) = 0.6*z + 0.4*|z|; folded: 0.6*(a.zi+a.zj) + sum_g sgn_g*|azi+azj|

// ws layout (floats):
//  h_ws   [8][512][64]         262144  @ 0
//  azi_ws [8][512][68]         278528  @ 262144
//  azj_ws [8][512][68]         278528  @ 540672
//  adi_ws [8][512]             4096    @ 819200
//  adj_ws [8][512]             4096    @ 823296
//  pacc   [16][8][512][64]     4194304 @ 827392
//  pm     [16][4096]           65536   @ 5021696
//  ps     [16][4096]           65536   @ 5087232

__device__ __forceinline__ float rdlane(float v, int idx) {
    return __int_as_float(__builtin_amdgcn_readlane(__float_as_int(v), idx));
}

// ---------------------------------------------------------------------------
// proj: r14 version (permuted azi/azj scatter) — validated. 512 blocks x 256.
// ---------------------------------------------------------------------------
__global__ __launch_bounds__(256) void proj_kernel(
    const float* __restrict__ x, const float* __restrict__ Wp,
    const float* __restrict__ bp, const float* __restrict__ Wc,
    const float* __restrict__ Wcb, const float* __restrict__ a,
    float* __restrict__ h_ws, float* __restrict__ azi_ws, float* __restrict__ azj_ws,
    float* __restrict__ adi_ws, float* __restrict__ adj_ws)
{
    int blk = blockIdx.x;
    int bh = blk >> 6;
    int n0 = (blk & 63) << 3;
    int b = bh >> 2, hh = bh & 3;

    __shared__ float xs[8 * FIN];
    __shared__ float hs[8][DD];
    __shared__ float Wcs[DD][2 * DD + 1];

    int t = threadIdx.x;

    ((float4*)xs)[t] = ((const float4*)(x + ((size_t)b * NN + n0) * FIN))[t];
    {
        const float4* wg = (const float4*)(Wc + (size_t)hh * DD * 2 * DD);
        #pragma unroll
        for (int k = 0; k < 8; ++k) {
            int idx = t + 256 * k;
            int r = idx >> 5, c4 = (idx & 31) * 4;
            float4 v = wg[idx];
            Wcs[r][c4] = v.x; Wcs[r][c4 + 1] = v.y;
            Wcs[r][c4 + 2] = v.z; Wcs[r][c4 + 3] = v.w;
        }
    }
    __syncthreads();

    int e = t & 63, w = t >> 6;            // rows w, w+4
    const float* Wph = Wp + (size_t)hh * FIN * DD;
    float bpv = bp[hh * DD + e];
    float acc0 = bpv, acc1 = bpv;
    #pragma unroll 8
    for (int i = 0; i < FIN; ++i) {
        float wv = Wph[i * DD + e];
        acc0 = fmaf(xs[w * FIN + i], wv, acc0);
        acc1 = fmaf(xs[(w + 4) * FIN + i], wv, acc1);
    }
    hs[w][e] = acc0; hs[w + 4][e] = acc1;
    float* hg = h_ws + ((size_t)bh * NN + n0) * DD;
    hg[w * DD + e] = acc0; hg[(w + 4) * DD + e] = acc1;
    __syncthreads();

    float zb = Wcb[hh * DD + e];
    float zi0 = zb, zi1 = zb, zj0 = 0.f, zj1 = 0.f;
    #pragma unroll 8
    for (int d2 = 0; d2 < DD; ++d2) {
        float w1 = Wcs[e][d2];
        float w2 = Wcs[e][DD + d2];
        float h0 = hs[w][d2], h1 = hs[w + 4][d2];
        zi0 = fmaf(h0, w1, zi0); zi1 = fmaf(h1, w1, zi1);
        zj0 = fmaf(h0, w2, zj0); zj1 = fmaf(h1, w2, zj1);
    }

    float av = a[hh * DD + e];
    float p0 = av * zi0, p1 = av * zi1, q0 = av * zj0, q1 = av * zj1;
    #pragma unroll
    for (int off = 32; off; off >>= 1) {
        p0 += __shfl_xor(p0, off); p1 += __shfl_xor(p1, off);
        q0 += __shfl_xor(q0, off); q1 += __shfl_xor(q1, off);
    }
    if (e == 0) {
        adi_ws[bh * NN + n0 + w]     = 0.6f * p0;
        adi_ws[bh * NN + n0 + w + 4] = 0.6f * p1;
        adj_ws[bh * NN + n0 + w]     = 0.6f * q0;
        adj_ws[bh * NN + n0 + w + 4] = 0.6f * q1;
    }

    unsigned long long mask = __ballot(av >= 0.f);
    int np = __popcll(mask);
    int GP = (np + 3) >> 2;
    int below = __popcll(mask & ((1ull << e) - 1ull));
    int slot = (av >= 0.f) ? below : (4 * GP + (e - below));
    float pav = __builtin_fabsf(av);

    float* azib = azi_ws + ((size_t)bh * NN + n0) * SW;
    float* azjb = azj_ws + ((size_t)bh * NN + n0) * SW;
    azib[w * SW + slot]       = pav * zi0;
    azib[(w + 4) * SW + slot] = pav * zi1;
    azjb[w * SW + slot]       = pav * zj0;
    azjb[(w + 4) * SW + slot] = pav * zj1;
    int p1c = 4 * GP - np;
    if (e < 4) {
        int psl = (e < p1c) ? (np + e) : (4 * GP + 64 - np + (e - p1c));
        azib[w * SW + psl] = 0.f; azib[(w + 4) * SW + psl] = 0.f;
        azjb[w * SW + psl] = 0.f; azjb[(w + 4) * SW + psl] = 0.f;
    }
}

// ---------------------------------------------------------------------------
// attn6v2: identical to r14's attn6 except phase 3 p-delivery:
// per-lane b32 + v_readlane (VALU pipe) instead of 4 uniform ds_read_b128.
// grid = 8bh x 8is x 16js = 1024 blocks x 256 thr.
// ---------------------------------------------------------------------------
#define AZJ 0        // [32][68] floats in smA
#define HT  2176     // [32][64]
#define ADJ 4224     // [32]
__global__ __launch_bounds__(256) void attn6v2(
    const float* __restrict__ h_ws, const float* __restrict__ azi_ws,
    const float* __restrict__ azj_ws, const float* __restrict__ adi_ws,
    const float* __restrict__ adj_ws, const float* __restrict__ a,
    float* __restrict__ pacc, float* __restrict__ pm, float* __restrict__ ps)
{
    int blk = blockIdx.x;
    int js = blk & 15, is_ = (blk >> 4) & 7, bh = blk >> 7;
    int i0 = is_ << 6, j0 = js << 5, hh = bh & 3;
    int t = threadIdx.x, lane = t & 63, w = t >> 6;

    __shared__ float smA[64 * 68];   // 17.4 KB: azi staging, then azj+h+adj
    __shared__ float eP[32 * 68];    // 8.7 KB: e then p, [j][i(+pad)]

    // ---- stage azi strip [64][68] (coalesced), then own row -> regs ----
    {
        const float4* src = (const float4*)(azi_ws + ((size_t)bh * NN + i0) * SW);
        float4* dst = (float4*)smA;
        #pragma unroll
        for (int k = 0; k < 5; ++k) {
            int idx = t + 256 * k;
            if (idx < 1088) dst[idx] = src[idx];
        }
    }
    __syncthreads();
    float4 azi4[17];
    #pragma unroll
    for (int k = 0; k < 17; ++k)
        azi4[k] = *(const float4*)&smA[lane * SW + 4 * k];
    float adiv = adi_ws[bh * NN + i0 + lane];
    __syncthreads();                 // azi staging region free

    // ---- stage azj [32][68] + h [32][64] + adj [32] (coalesced) ----
    {
        const float4* sj = (const float4*)(azj_ws + ((size_t)bh * NN + j0) * SW);
        #pragma unroll
        for (int k = 0; k < 3; ++k) {
            int idx = t + 256 * k;
            if (idx < 544) ((float4*)&smA[AZJ])[idx] = sj[idx];
        }
        const float4* sh = (const float4*)(h_ws + ((size_t)bh * NN + j0) * DD);
        ((float4*)&smA[HT])[t]       = sh[t];
        ((float4*)&smA[HT])[t + 256] = sh[t + 256];
        if (t < 32) smA[ADJ + t] = adj_ws[bh * NN + j0 + t];
    }

    float av_e = a[hh * DD + lane];
    unsigned long long mask = __ballot(av_e >= 0.f);
    int GP = (__popcll(mask) + 3) >> 2;

    __syncthreads();

    // ---- phase 1: scores. wave w does j = 8w..8w+7, lane = i ----
    #pragma unroll
    for (int jj = 0; jj < 8; ++jj) {
        int j = 8 * w + jj;
        const float4* aj = (const float4*)&smA[AZJ + j * SW];   // uniform b128
        float adjv = smA[ADJ + j];                              // uniform
        float c0 = 0.f, c1 = 0.f, c2 = 0.f, c3 = 0.f;
        #pragma unroll
        for (int k = 0; k < 17; ++k) {
            float4 A = aj[k];
            float sg = (k < GP) ? 0.4f : -0.4f;
            c0 = fmaf(sg, __builtin_fabsf(azi4[k].x + A.x), c0);
            c1 = fmaf(sg, __builtin_fabsf(azi4[k].y + A.y), c1);
            c2 = fmaf(sg, __builtin_fabsf(azi4[k].z + A.z), c2);
            c3 = fmaf(sg, __builtin_fabsf(azi4[k].w + A.w), c3);
        }
        eP[j * SW + lane] = adiv + adjv + ((c0 + c1) + (c2 + c3));
    }
    __syncthreads();

    // ---- phase 2: softmax. lane (il, jq): row iL = 16w + il, 8 j each ----
    {
        int il = lane & 15, jq = lane >> 4;
        int iL = 16 * w + il;
        float e8[8];
        float m = -1e30f;
        #pragma unroll
        for (int jj = 0; jj < 8; ++jj) {
            e8[jj] = eP[(jq * 8 + jj) * SW + iL];
            m = fmaxf(m, e8[jj]);
        }
        m = fmaxf(m, __shfl_xor(m, 16));
        m = fmaxf(m, __shfl_xor(m, 32));
        float s = 0.f;
        #pragma unroll
        for (int jj = 0; jj < 8; ++jj) {
            float p = __expf(e8[jj] - m);
            s += p;
            eP[(jq * 8 + jj) * SW + iL] = p;
        }
        s += __shfl_xor(s, 16);
        s += __shfl_xor(s, 32);
        if (jq == 0) {
            pm[js * 4096 + bh * NN + i0 + iL] = m;
            ps[js * 4096 + bh * NN + i0 + iL] = s;
        }
    }
    __syncthreads();

    // ---- phase 3: PV. wave w: i = 16w..16w+15, lane = d.
    //      p via per-lane b32 (16 addrs x4 broadcast) + readlane (VALU). ----
    float acc[16];
    #pragma unroll
    for (int ii = 0; ii < 16; ++ii) acc[ii] = 0.f;
    #pragma unroll 8
    for (int j = 0; j < 32; ++j) {
        float vh = smA[HT + j * 64 + lane];               // per-lane b32
        float vp = eP[j * SW + 16 * w + (lane & 15)];     // b32, conflict-free
        #pragma unroll
        for (int ii = 0; ii < 16; ++ii)
            acc[ii] = fmaf(rdlane(vp, ii), vh, acc[ii]);  // VALU pipe
    }

    // ---- store partials (coalesced: lane = d) ----
    float* pb = pacc + ((size_t)(js * 8 + bh) * NN + i0 + 16 * w) * DD + lane;
    #pragma unroll
    for (int ii = 0; ii < 16; ++ii)
        pb[(size_t)ii * DD] = acc[ii];
}

// ---------------------------------------------------------------------------
// combine 16 j-splits + bias (validated r12-r19). grid = 1024 x 256.
// ---------------------------------------------------------------------------
__global__ __launch_bounds__(256) void combine_kernel(
    const float* __restrict__ pacc, const float* __restrict__ pm,
    const float* __restrict__ ps, const float* __restrict__ bias_param,
    float* __restrict__ out)
{
    int tid = blockIdx.x * 256 + threadIdx.x;
    int d = tid & 63;
    int row = tid >> 6;
    int bh = row >> 9, n = row & 511;
    int b = bh >> 2, hh = bh & 3;
    float mv[16];
    float m = -1e30f;
    #pragma unroll
    for (int p = 0; p < 16; ++p) { mv[p] = pm[p * 4096 + row]; m = fmaxf(m, mv[p]); }
    float denom = 0.f, acc = 0.f;
    #pragma unroll
    for (int p = 0; p < 16; ++p) {
        float wgt = __expf(mv[p] - m);
        denom = fmaf(ps[p * 4096 + row], wgt, denom);
        acc = fmaf(pacc[(size_t)p * 262144 + (size_t)row * 64 + d], wgt, acc);
    }
    out[((size_t)b * NN + n) * (HH * DD) + hh * DD + d] =
        acc / denom + bias_param[hh * DD + d];
}

extern "C" void kernel_launch(void* const* d_in, const int* in_sizes, int n_in,
                              void* d_out, int out_size, void* d_ws, size_t ws_size,
                              hipStream_t stream) {
    const float* x    = (const float*)d_in[0];
    const float* Wp   = (const float*)d_in[1];
    const float* bp   = (const float*)d_in[2];
    const float* Wc   = (const float*)d_in[3];
    const float* Wcb  = (const float*)d_in[4];
    const float* a    = (const float*)d_in[5];
    const float* bpar = (const float*)d_in[6];
    float* out = (float*)d_out;

    float* ws     = (float*)d_ws;
    float* h_ws   = ws;
    float* azi_ws = ws + 262144;
    float* azj_ws = ws + 540672;
    float* adi_ws = ws + 819200;
    float* adj_ws = ws + 823296;
    float* pacc   = ws + 827392;
    float* pm     = ws + 5021696;
    float* ps     = ws + 5087232;

    proj_kernel<<<dim3(512), dim3(256), 0, stream>>>(
        x, Wp, bp, Wc, Wcb, a, h_ws, azi_ws, azj_ws, adi_ws, adj_ws);
    attn6v2<<<dim3(1024), dim3(256), 0, stream>>>(
        h_ws, azi_ws, azj_ws, adi_ws, adj_ws, a, pacc, pm, ps);
    combine_kernel<<<dim3(1024), dim3(256), 0, stream>>>(
        pacc, pm, ps, bpar, out);
}